// Round 3
// baseline (539.770 us; speedup 1.0000x reference)
//
#include <hip/hip_runtime.h>
#include <math.h>

#define NB 50000
#define NE 600000
#define NG 2000
#define ND 64
#define HID 128
#define BN_EPS 1e-5f
#define NBLK 196        // ceil(NB/256)
#define MPAD 50176      // 392*128, padded rows for GEMM tiles

typedef __attribute__((ext_vector_type(8))) short bf16x8;
typedef __attribute__((ext_vector_type(4))) float f32x4;
typedef unsigned int uint;
typedef unsigned short ushort;

__device__ __forceinline__ ushort f2b(float f) {
  uint u = __builtin_bit_cast(uint, f);
  u = u + 0x7fffu + ((u >> 16) & 1u);   // RNE
  return (ushort)(u >> 16);
}
__device__ __forceinline__ float blo(uint u) {
  return __builtin_bit_cast(float, u << 16);
}
__device__ __forceinline__ float bhi(uint u) {
  return __builtin_bit_cast(float, u & 0xffff0000u);
}

// ---------------- degree / normalization ----------------
__global__ __launch_bounds__(256) void deg_kernel(const int* __restrict__ dst,
                                                  int* __restrict__ cnt) {
  int e = blockIdx.x * 256 + threadIdx.x;
  if (e < NE) atomicAdd(&cnt[dst[e]], 1);
}

__global__ __launch_bounds__(256) void dis_kernel(const int* __restrict__ cnt,
                                                  float* __restrict__ dis) {
  int v = blockIdx.x * 256 + threadIdx.x;
  if (v < NB) dis[v] = rsqrtf((float)(cnt[v] + 1));  // +1 self-loop
}

// ---------------- prefix scan ----------------
__global__ __launch_bounds__(256) void scan1(const int* __restrict__ cnt,
                                             int* __restrict__ part,
                                             int* __restrict__ bsum) {
  __shared__ int tmp[256];
  int tid = threadIdx.x;
  int i = blockIdx.x * 256 + tid;
  int v = (i < NB) ? cnt[i] : 0;
  tmp[tid] = v;
  __syncthreads();
  for (int off = 1; off < 256; off <<= 1) {
    int t = (tid >= off) ? tmp[tid - off] : 0;
    __syncthreads();
    tmp[tid] += t;
    __syncthreads();
  }
  if (i < NB) part[i] = tmp[tid] - v;
  if (tid == 255) bsum[blockIdx.x] = tmp[255];
}

__global__ __launch_bounds__(256) void scan2(int* __restrict__ bsum,
                                             int* __restrict__ boffs) {
  __shared__ int tmp[256];
  int tid = threadIdx.x;
  int v = (tid < NBLK) ? bsum[tid] : 0;
  tmp[tid] = v;
  __syncthreads();
  for (int off = 1; off < 256; off <<= 1) {
    int t = (tid >= off) ? tmp[tid - off] : 0;
    __syncthreads();
    tmp[tid] += t;
    __syncthreads();
  }
  if (tid < NBLK) boffs[tid] = tmp[tid] - v;
}

__global__ __launch_bounds__(256) void scan3(int* __restrict__ part,
                                             const int* __restrict__ boffs) {
  int i = blockIdx.x * 256 + threadIdx.x;
  if (i < NB) part[i] += boffs[blockIdx.x];
  if (i == 0) part[NB] = NE;
}

// ---------------- CSR fill ----------------
__global__ __launch_bounds__(256) void fill_csr(const int* __restrict__ src,
                                                const int* __restrict__ dst,
                                                const float* __restrict__ dis,
                                                const int* __restrict__ row_ptr,
                                                int* __restrict__ cursor,
                                                int* __restrict__ e_src,
                                                float* __restrict__ e_w) {
  int e = blockIdx.x * 256 + threadIdx.x;
  if (e >= NE) return;
  int s = src[e], d = dst[e];
  int pos = row_ptr[d] + atomicAdd(&cursor[d], 1);
  e_src[pos] = s;
  e_w[pos] = dis[s] * dis[d];
}

// ---------------- input f32 -> bf16 ----------------
__global__ __launch_bounds__(256) void cvt_x(const float* __restrict__ x,
                                             ushort* __restrict__ xb) {
  int i = blockIdx.x * 256 + threadIdx.x;
  if (i >= NB * ND / 4) return;
  float4 v = reinterpret_cast<const float4*>(x)[i];
  ushort4 o;
  o.x = f2b(v.x); o.y = f2b(v.y); o.z = f2b(v.z); o.w = f2b(v.w);
  reinterpret_cast<ushort4*>(xb)[i] = o;
}

// ---------------- weight prep: BN fold + MFMA fragment packing ------------
// Wsrc: f32 [K][128] row-major. Output: Bp bf16 packed as
// index ((nf*nkf + kf)*64 + lane)*8 + j  ->  W[kf*32+(lane>>4)*8+j][nf*16+(lane&15)]
// with per-row scale a[k]; bias_out[n] = bias_in[n] + sum_k bmu[k]*W[k][n].
__global__ __launch_bounds__(128) void prep_w(const float* __restrict__ W, int K,
                                              const float* __restrict__ stats,
                                              const float* __restrict__ gamma,
                                              const float* __restrict__ beta,
                                              const float* __restrict__ bias_in,
                                              ushort* __restrict__ Bp,
                                              float* __restrict__ bias_out) {
  __shared__ float a_s[128], b_s[128];
  int t = threadIdx.x;
  float a = 1.f, bm = 0.f;
  if (stats != nullptr) {
    float mu = stats[t] * (1.f / NB);
    float var = stats[128 + t] * (1.f / NB) - mu * mu;
    a = gamma[t] * rsqrtf(var + BN_EPS);
    bm = beta[t] - mu * a;
  }
  if (t < K) { a_s[t] = a; b_s[t] = bm; }
  __syncthreads();
  float acc = bias_in ? bias_in[t] : 0.f;
  for (int k = 0; k < K; k++) acc += b_s[k] * W[k * 128 + t];
  bias_out[t] = acc;
  int nkf = K >> 5;
  int total = nkf * 4096;  // 8 nf * nkf * 64 * 8
  for (int i = t; i < total; i += 128) {
    int j = i & 7;
    int lane = (i >> 3) & 63;
    int rem = i >> 9;          // nf*nkf + kf
    int kf = rem % nkf;
    int nf = rem / nkf;
    int k = kf * 32 + (lane >> 4) * 8 + j;
    int col = nf * 16 + (lane & 15);
    Bp[i] = f2b(a_s[k] * W[k * 128 + col]);
  }
}

// ---------------- bf16 MFMA GEMM: C[M,128] = A[M,K] @ Bp (+bias, opt relu) -
// BM=128, 256 threads = 4 waves, each wave 32 rows (2 m-frags x 8 n-frags).
template <bool RELU>
__global__ __launch_bounds__(256) void gemm_mfma(const ushort* __restrict__ A,
                                                 const ushort* __restrict__ Bp,
                                                 const float* __restrict__ bias,
                                                 ushort* __restrict__ C, int M,
                                                 int K) {
  __shared__ ushort Blds[16384];  // up to 32KB (K=128)
  const int tid = threadIdx.x;
  const int lane = tid & 63;
  const int w = tid >> 6;
  const int nkf = K >> 5;
  // stage packed B into LDS (16B per thread-iter)
  for (int i = tid; i < nkf * 512; i += 256)
    reinterpret_cast<uint4*>(Blds)[i] = reinterpret_cast<const uint4*>(Bp)[i];
  __syncthreads();

  const int rbase = blockIdx.x * 128 + w * 32;
  f32x4 acc[2][8];
#pragma unroll
  for (int m = 0; m < 2; m++)
#pragma unroll
    for (int n = 0; n < 8; n++) acc[m][n] = (f32x4){0.f, 0.f, 0.f, 0.f};

  const int arow0 = rbase + (lane & 15);
  const int acol = (lane >> 4) * 8;
#pragma unroll 4
  for (int kf = 0; kf < nkf; kf++) {
    bf16x8 a0 = *reinterpret_cast<const bf16x8*>(
        A + (size_t)arow0 * K + kf * 32 + acol);
    bf16x8 a1 = *reinterpret_cast<const bf16x8*>(
        A + (size_t)(arow0 + 16) * K + kf * 32 + acol);
#pragma unroll
    for (int nf = 0; nf < 8; nf++) {
      bf16x8 b = *reinterpret_cast<const bf16x8*>(
          &Blds[((nf * nkf + kf) * 64 + lane) * 8]);
      acc[0][nf] = __builtin_amdgcn_mfma_f32_16x16x32_bf16(a0, b, acc[0][nf], 0, 0, 0);
      acc[1][nf] = __builtin_amdgcn_mfma_f32_16x16x32_bf16(a1, b, acc[1][nf], 0, 0, 0);
    }
  }

#pragma unroll
  for (int m = 0; m < 2; m++) {
    int row0 = rbase + m * 16 + (lane >> 4) * 4;
#pragma unroll
    for (int nf = 0; nf < 8; nf++) {
      int col = nf * 16 + (lane & 15);
      float bv = bias[col];
#pragma unroll
      for (int r = 0; r < 4; r++) {
        int row = row0 + r;
        if (row < M) {
          float v = acc[m][nf][r] + bv;
          if (RELU) v = fmaxf(v, 0.f);
          C[(size_t)row * 128 + col] = f2b(v);
        }
      }
    }
  }
}

// ---------------- conv aggregation: CSR gather (bf16 h) -------------------
// y[v] = relu(bias + h[v]*dis[v]^2 + sum_e h[e_src]*e_w), 16 lanes/node x 8ch
__global__ __launch_bounds__(256) void gather_conv(
    const ushort* __restrict__ h, const int* __restrict__ e_src,
    const float* __restrict__ e_w, const int* __restrict__ row_ptr,
    const float* __restrict__ dis, const float* __restrict__ bias,
    ushort* __restrict__ y) {
  int gid = blockIdx.x * 256 + threadIdx.x;
  int v = gid >> 4;
  if (v >= NB) return;
  int c8 = gid & 15;
  const uint4* h4 = reinterpret_cast<const uint4*>(h);
  float s = dis[v];
  float ss = s * s;
  uint4 hv = h4[(size_t)v * 16 + c8];
  float acc[8];
  acc[0] = bias[c8 * 8 + 0] + blo(hv.x) * ss;
  acc[1] = bias[c8 * 8 + 1] + bhi(hv.x) * ss;
  acc[2] = bias[c8 * 8 + 2] + blo(hv.y) * ss;
  acc[3] = bias[c8 * 8 + 3] + bhi(hv.y) * ss;
  acc[4] = bias[c8 * 8 + 4] + blo(hv.z) * ss;
  acc[5] = bias[c8 * 8 + 5] + bhi(hv.z) * ss;
  acc[6] = bias[c8 * 8 + 6] + blo(hv.w) * ss;
  acc[7] = bias[c8 * 8 + 7] + bhi(hv.w) * ss;
  int beg = row_ptr[v], end = row_ptr[v + 1];
  for (int e = beg; e < end; ++e) {
    int si = e_src[e];
    float ew = e_w[e];
    uint4 q = h4[(size_t)si * 16 + c8];
    acc[0] += blo(q.x) * ew;
    acc[1] += bhi(q.x) * ew;
    acc[2] += blo(q.y) * ew;
    acc[3] += bhi(q.y) * ew;
    acc[4] += blo(q.z) * ew;
    acc[5] += bhi(q.z) * ew;
    acc[6] += blo(q.w) * ew;
    acc[7] += bhi(q.w) * ew;
  }
  uint4 o;
  o.x = (uint)f2b(fmaxf(acc[0], 0.f)) | ((uint)f2b(fmaxf(acc[1], 0.f)) << 16);
  o.y = (uint)f2b(fmaxf(acc[2], 0.f)) | ((uint)f2b(fmaxf(acc[3], 0.f)) << 16);
  o.z = (uint)f2b(fmaxf(acc[4], 0.f)) | ((uint)f2b(fmaxf(acc[5], 0.f)) << 16);
  o.w = (uint)f2b(fmaxf(acc[6], 0.f)) | ((uint)f2b(fmaxf(acc[7], 0.f)) << 16);
  reinterpret_cast<uint4*>(y)[(size_t)v * 16 + c8] = o;
}

// ---------------- per-channel stats from bf16 y ---------------------------
__global__ __launch_bounds__(256) void stats_kernel(const ushort* __restrict__ y,
                                                    float* __restrict__ stats) {
  __shared__ float red[2048];  // 256 threads x 8 channels
  int tid = threadIdx.x;
  float sum[8], sq[8];
#pragma unroll
  for (int j = 0; j < 8; j++) { sum[j] = 0.f; sq[j] = 0.f; }
  const uint4* y4 = reinterpret_cast<const uint4*>(y);
  for (int i = blockIdx.x * 256 + tid; i < NB * 16; i += gridDim.x * 256) {
    uint4 q = y4[i];
    float v0 = blo(q.x), v1 = bhi(q.x), v2 = blo(q.y), v3 = bhi(q.y);
    float v4 = blo(q.z), v5 = bhi(q.z), v6 = blo(q.w), v7 = bhi(q.w);
    sum[0] += v0; sq[0] += v0 * v0;
    sum[1] += v1; sq[1] += v1 * v1;
    sum[2] += v2; sq[2] += v2 * v2;
    sum[3] += v3; sq[3] += v3 * v3;
    sum[4] += v4; sq[4] += v4 * v4;
    sum[5] += v5; sq[5] += v5 * v5;
    sum[6] += v6; sq[6] += v6 * v6;
    sum[7] += v7; sq[7] += v7 * v7;
  }
  int cg = tid & 15;  // channel group: channels cg*8..cg*8+7
  // pass 1: sums
#pragma unroll
  for (int j = 0; j < 8; j++) red[tid * 8 + j] = sum[j];
  __syncthreads();
  for (int s = 128; s >= 16; s >>= 1) {
    if (tid < s)
#pragma unroll
      for (int j = 0; j < 8; j++) red[tid * 8 + j] += red[(tid + s) * 8 + j];
    __syncthreads();
  }
  if (tid < 16)
#pragma unroll
    for (int j = 0; j < 8; j++) atomicAdd(&stats[cg * 8 + j], red[tid * 8 + j]);
  __syncthreads();
  // pass 2: sumsq
#pragma unroll
  for (int j = 0; j < 8; j++) red[tid * 8 + j] = sq[j];
  __syncthreads();
  for (int s = 128; s >= 16; s >>= 1) {
    if (tid < s)
#pragma unroll
      for (int j = 0; j < 8; j++) red[tid * 8 + j] += red[(tid + s) * 8 + j];
    __syncthreads();
  }
  if (tid < 16)
#pragma unroll
    for (int j = 0; j < 8; j++)
      atomicAdd(&stats[128 + cg * 8 + j], red[tid * 8 + j]);
}

// ---------------- pooling ----------------
__global__ __launch_bounds__(256) void graph_bounds(const int* __restrict__ batch,
                                                    int* __restrict__ g_start) {
  int g = blockIdx.x * 256 + threadIdx.x;
  if (g > NG) return;
  if (g == NG) { g_start[NG] = NB; return; }
  int lo = 0, hi = NB;
  while (lo < hi) {
    int mid = (lo + hi) >> 1;
    if (batch[mid] < g) lo = mid + 1; else hi = mid;
  }
  g_start[g] = lo;
}

__global__ __launch_bounds__(256) void pool_gather(const ushort* __restrict__ emb,
                                                   const int* __restrict__ g_start,
                                                   float* __restrict__ g) {
  int gid = blockIdx.x * 256 + threadIdx.x;
  int gr = gid >> 4;
  if (gr >= NG) return;
  int c8 = gid & 15;
  const uint4* e4 = reinterpret_cast<const uint4*>(emb);
  float acc[8];
#pragma unroll
  for (int j = 0; j < 8; j++) acc[j] = 0.f;
  int beg = g_start[gr], end = g_start[gr + 1];
  for (int v = beg; v < end; ++v) {
    uint4 q = e4[(size_t)v * 16 + c8];
    acc[0] += blo(q.x); acc[1] += bhi(q.x);
    acc[2] += blo(q.y); acc[3] += bhi(q.y);
    acc[4] += blo(q.z); acc[5] += bhi(q.z);
    acc[6] += blo(q.w); acc[7] += bhi(q.w);
  }
  float4* gp = reinterpret_cast<float4*>(g + (size_t)gr * 128 + c8 * 8);
  gp[0] = make_float4(acc[0], acc[1], acc[2], acc[3]);
  gp[1] = make_float4(acc[4], acc[5], acc[6], acc[7]);
}

// ---------------- head: 8 graphs per block, weights in LDS ----------------
__global__ __launch_bounds__(128) void head_kernel(
    const float* __restrict__ g, const float* __restrict__ w1,
    const float* __restrict__ b1, const float* __restrict__ w2,
    const float* __restrict__ b2, const float* __restrict__ wp,
    const float* __restrict__ bp, float* __restrict__ out) {
  __shared__ float w1s[128 * 64];
  __shared__ float w2s[64 * 32];
  __shared__ float wps[64];
  __shared__ float sg[128], ph[128], sh1[64], sh2[32];
  int tid = threadIdx.x;
  for (int i = tid; i < 2048; i += 128)
    reinterpret_cast<float4*>(w1s)[i] = reinterpret_cast<const float4*>(w1)[i];
  for (int i = tid; i < 512; i += 128)
    reinterpret_cast<float4*>(w2s)[i] = reinterpret_cast<const float4*>(w2)[i];
  if (tid < 64) wps[tid] = wp[tid];
  __syncthreads();

  for (int gi = 0; gi < 8; gi++) {
    int gid = blockIdx.x * 8 + gi;
    if (gid >= NG) break;
    sg[tid] = g[(size_t)gid * 128 + tid];
    __syncthreads();
    // layer1: 64 outputs x 2 k-halves
    {
      int o = tid & 63, h = tid >> 6;
      float acc = 0.f;
#pragma unroll 8
      for (int k = 0; k < 64; k++) acc += sg[h * 64 + k] * w1s[(h * 64 + k) * 64 + o];
      ph[tid] = acc;
    }
    __syncthreads();
    if (tid < 64) sh1[tid] = fmaxf(b1[tid] + ph[tid] + ph[tid + 64], 0.f);
    __syncthreads();
    // layer2: 32 outputs x 4 k-slices
    {
      int o = tid & 31, q = tid >> 5;
      float acc = 0.f;
#pragma unroll 8
      for (int k = 0; k < 16; k++) acc += sh1[q * 16 + k] * w2s[(q * 16 + k) * 32 + o];
      ph[tid] = acc;
    }
    __syncthreads();
    if (tid < 32)
      sh2[tid] = fmaxf(b2[tid] + ph[tid] + ph[tid + 32] + ph[tid + 64] + ph[tid + 96], 0.f);
    __syncthreads();
    if (tid < 2) {
      float acc = bp[tid];
#pragma unroll
      for (int k = 0; k < 32; k++) acc += sh2[k] * wps[k * 2 + tid];
      out[(size_t)gid * 2 + tid] = acc;
    }
    __syncthreads();
  }
}

extern "C" void kernel_launch(void* const* d_in, const int* in_sizes, int n_in,
                              void* d_out, int out_size, void* d_ws,
                              size_t ws_size, hipStream_t stream) {
  const float* x = (const float*)d_in[0];
  const int* ei = (const int*)d_in[1];
  const int* batch = (const int*)d_in[2];
  const float* lin_w = (const float*)d_in[3];
  const float* lin_b = (const float*)d_in[4];
  const float* conv_w = (const float*)d_in[5];
  const float* conv_b = (const float*)d_in[6];
  const float* bn_g = (const float*)d_in[7];
  const float* bn_b = (const float*)d_in[8];
  const float* emb_w = (const float*)d_in[9];
  const float* emb_b = (const float*)d_in[10];
  const float* m1w = (const float*)d_in[11];
  const float* m1b = (const float*)d_in[12];
  const float* m2w = (const float*)d_in[13];
  const float* m2b = (const float*)d_in[14];
  const float* pw = (const float*)d_in[15];
  const float* pb = (const float*)d_in[16];
  float* out = (float*)d_out;

  ushort* buf0 = (ushort*)d_ws;                  // [MPAD,128] bf16
  ushort* buf1 = buf0 + (size_t)MPAD * 128;      // [MPAD,128] bf16
  ushort* xb = buf1 + (size_t)MPAD * 128;        // [MPAD,64] bf16
  ushort* Bp = xb + (size_t)MPAD * 64;           // 5 * 16384 packed weights
  float* fbase = (float*)(Bp + 5 * 16384);
  float* dis = fbase;                            // [NB] pad 50048
  float* statsb = dis + 50048;                   // [3*256]
  float* biasb = statsb + 768;                   // [5*128]
  float* e_w = biasb + 640;                      // [NE]
  float* g = e_w + NE;                           // [NG*128]
  int* cnt = (int*)(g + (size_t)NG * 128);       // [NB]
  int* row_ptr = cnt + NB;                       // [NB+1] pad 50008
  int* cursor = row_ptr + 50008;                 // [NB]
  int* e_src = cursor + NB;                      // [NE]
  int* bsum = e_src + NE;                        // [256]
  int* boffs = bsum + 256;                       // [256]
  int* g_start = boffs + 256;                    // [NG+1]

  const int* src = ei;
  const int* dst = ei + NE;

  hipMemsetAsync(cnt, 0, NB * sizeof(int), stream);
  hipMemsetAsync(cursor, 0, NB * sizeof(int), stream);
  hipMemsetAsync(statsb, 0, 768 * sizeof(float), stream);

  deg_kernel<<<(NE + 255) / 256, 256, 0, stream>>>(dst, cnt);
  dis_kernel<<<NBLK, 256, 0, stream>>>(cnt, dis);
  scan1<<<NBLK, 256, 0, stream>>>(cnt, row_ptr, bsum);
  scan2<<<1, 256, 0, stream>>>(bsum, boffs);
  scan3<<<NBLK, 256, 0, stream>>>(row_ptr, boffs);
  fill_csr<<<(NE + 255) / 256, 256, 0, stream>>>(src, dst, dis, row_ptr, cursor,
                                                 e_src, e_w);
  graph_bounds<<<(NG + 256) / 256, 256, 0, stream>>>(batch, g_start);

  cvt_x<<<(NB * ND / 4 + 255) / 256, 256, 0, stream>>>(x, xb);

  ushort* Bp0 = Bp;                // lin (K=64, only 8192 used)
  ushort* Bp1 = Bp + 16384;        // conv0
  ushort* Bp2 = Bp + 2 * 16384;    // conv1 (BN0 folded)
  ushort* Bp3 = Bp + 3 * 16384;    // conv2 (BN1 folded)
  ushort* Bp4 = Bp + 4 * 16384;    // emb  (BN2 folded)
  float* bias0 = biasb;
  float* bias1 = biasb + 128;
  float* bias2 = biasb + 256;
  float* bias3 = biasb + 384;
  float* bias4 = biasb + 512;

  prep_w<<<1, 128, 0, stream>>>(lin_w, 64, nullptr, nullptr, nullptr, lin_b,
                                Bp0, bias0);
  prep_w<<<1, 128, 0, stream>>>(conv_w, 128, nullptr, nullptr, nullptr,
                                nullptr, Bp1, bias1);

  const int GB = (NB + 127) / 128;  // gemm blocks

  // linatoms
  gemm_mfma<false><<<GB, 256, 0, stream>>>(xb, Bp0, bias0, buf0, NB, 64);

  // layer 0
  gemm_mfma<false><<<GB, 256, 0, stream>>>(buf0, Bp1, bias1, buf1, NB, 128);
  gather_conv<<<(NB * 16 + 255) / 256, 256, 0, stream>>>(
      buf1, e_src, e_w, row_ptr, dis, conv_b, buf0);
  stats_kernel<<<256, 256, 0, stream>>>(buf0, statsb);
  prep_w<<<1, 128, 0, stream>>>(conv_w + 16384, 128, statsb, bn_g, bn_b,
                                nullptr, Bp2, bias2);
  // layer 1
  gemm_mfma<false><<<GB, 256, 0, stream>>>(buf0, Bp2, bias2, buf1, NB, 128);
  gather_conv<<<(NB * 16 + 255) / 256, 256, 0, stream>>>(
      buf1, e_src, e_w, row_ptr, dis, conv_b + 128, buf0);
  stats_kernel<<<256, 256, 0, stream>>>(buf0, statsb + 256);
  prep_w<<<1, 128, 0, stream>>>(conv_w + 2 * 16384, 128, statsb + 256,
                                bn_g + 128, bn_b + 128, nullptr, Bp3, bias3);
  // layer 2
  gemm_mfma<false><<<GB, 256, 0, stream>>>(buf0, Bp3, bias3, buf1, NB, 128);
  gather_conv<<<(NB * 16 + 255) / 256, 256, 0, stream>>>(
      buf1, e_src, e_w, row_ptr, dis, conv_b + 256, buf0);
  stats_kernel<<<256, 256, 0, stream>>>(buf0, statsb + 512);
  prep_w<<<1, 128, 0, stream>>>(emb_w, 128, statsb + 512, bn_g + 256,
                                bn_b + 256, emb_b, Bp4, bias4);
  // emb + pool + head
  gemm_mfma<true><<<GB, 256, 0, stream>>>(buf0, Bp4, bias4, buf1, NB, 128);
  pool_gather<<<(NG * 16 + 255) / 256, 256, 0, stream>>>(buf1, g_start, g);
  head_kernel<<<(NG + 7) / 8, 128, 0, stream>>>(g, m1w, m1b, m2w, m2b, pw, pb,
                                                out);
}

// Round 4
// 400.752 us; speedup vs baseline: 1.3469x; 1.3469x over previous
//
#include <hip/hip_runtime.h>
#include <math.h>

#define NB 50000
#define NE 600000
#define NG 2000
#define ND 64
#define HID 128
#define BN_EPS 1e-5f
#define NBLK 196        // ceil(NB/256)
#define MPAD 50176      // 392*128, padded rows for GEMM tiles
#define GATHER_BLKS 3125  // NB*16/256 exactly
#define RED_L1_BLKS 125   // 3125/25

typedef __attribute__((ext_vector_type(8))) short bf16x8;
typedef __attribute__((ext_vector_type(4))) float f32x4;
typedef unsigned int uint;
typedef unsigned short ushort;

__device__ __forceinline__ ushort f2b(float f) {
  uint u = __builtin_bit_cast(uint, f);
  u = u + 0x7fffu + ((u >> 16) & 1u);   // RNE
  return (ushort)(u >> 16);
}
__device__ __forceinline__ float blo(uint u) {
  return __builtin_bit_cast(float, u << 16);
}
__device__ __forceinline__ float bhi(uint u) {
  return __builtin_bit_cast(float, u & 0xffff0000u);
}

// ---------------- degree / normalization ----------------
__global__ __launch_bounds__(256) void deg_kernel(const int* __restrict__ dst,
                                                  int* __restrict__ cnt) {
  int e = blockIdx.x * 256 + threadIdx.x;
  if (e < NE) atomicAdd(&cnt[dst[e]], 1);
}

__global__ __launch_bounds__(256) void dis_kernel(const int* __restrict__ cnt,
                                                  float* __restrict__ dis) {
  int v = blockIdx.x * 256 + threadIdx.x;
  if (v < NB) dis[v] = rsqrtf((float)(cnt[v] + 1));  // +1 self-loop
}

// ---------------- prefix scan ----------------
__global__ __launch_bounds__(256) void scan1(const int* __restrict__ cnt,
                                             int* __restrict__ part,
                                             int* __restrict__ bsum) {
  __shared__ int tmp[256];
  int tid = threadIdx.x;
  int i = blockIdx.x * 256 + tid;
  int v = (i < NB) ? cnt[i] : 0;
  tmp[tid] = v;
  __syncthreads();
  for (int off = 1; off < 256; off <<= 1) {
    int t = (tid >= off) ? tmp[tid - off] : 0;
    __syncthreads();
    tmp[tid] += t;
    __syncthreads();
  }
  if (i < NB) part[i] = tmp[tid] - v;
  if (tid == 255) bsum[blockIdx.x] = tmp[255];
}

__global__ __launch_bounds__(256) void scan2(int* __restrict__ bsum,
                                             int* __restrict__ boffs) {
  __shared__ int tmp[256];
  int tid = threadIdx.x;
  int v = (tid < NBLK) ? bsum[tid] : 0;
  tmp[tid] = v;
  __syncthreads();
  for (int off = 1; off < 256; off <<= 1) {
    int t = (tid >= off) ? tmp[tid - off] : 0;
    __syncthreads();
    tmp[tid] += t;
    __syncthreads();
  }
  if (tid < NBLK) boffs[tid] = tmp[tid] - v;
}

__global__ __launch_bounds__(256) void scan3(int* __restrict__ part,
                                             const int* __restrict__ boffs) {
  int i = blockIdx.x * 256 + threadIdx.x;
  if (i < NB) part[i] += boffs[blockIdx.x];
  if (i == 0) part[NB] = NE;
}

// ---------------- CSR fill ----------------
__global__ __launch_bounds__(256) void fill_csr(const int* __restrict__ src,
                                                const int* __restrict__ dst,
                                                const float* __restrict__ dis,
                                                const int* __restrict__ row_ptr,
                                                int* __restrict__ cursor,
                                                int* __restrict__ e_src,
                                                float* __restrict__ e_w) {
  int e = blockIdx.x * 256 + threadIdx.x;
  if (e >= NE) return;
  int s = src[e], d = dst[e];
  int pos = row_ptr[d] + atomicAdd(&cursor[d], 1);
  e_src[pos] = s;
  e_w[pos] = dis[s] * dis[d];
}

// ---------------- input f32 -> bf16 ----------------
__global__ __launch_bounds__(256) void cvt_x(const float* __restrict__ x,
                                             ushort* __restrict__ xb) {
  int i = blockIdx.x * 256 + threadIdx.x;
  if (i >= NB * ND / 4) return;
  float4 v = reinterpret_cast<const float4*>(x)[i];
  ushort4 o;
  o.x = f2b(v.x); o.y = f2b(v.y); o.z = f2b(v.z); o.w = f2b(v.w);
  reinterpret_cast<ushort4*>(xb)[i] = o;
}

// ---------------- weight prep: stats finalize + BN fold + MFMA packing ----
// partial2: [125][256] per-block stat partials (sum[128], sumsq[128]).
// Bp layout: ((nf*nkf + kf)*64 + lane)*8 + j  ->
//            a[k] * W[kf*32+(lane>>4)*8+j][nf*16+(lane&15)]
// bias_out[n] = bias_in[n] + sum_k bmu[k]*W[k][n].
__global__ __launch_bounds__(256) void prep_w(const float* __restrict__ W, int K,
                                              const float* __restrict__ partial2,
                                              const float* __restrict__ gamma,
                                              const float* __restrict__ beta,
                                              const float* __restrict__ bias_in,
                                              ushort* __restrict__ Bp,
                                              float* __restrict__ bias_out) {
  __shared__ float a_s[128], b_s[128], red[256];
  int t = threadIdx.x;
  if (partial2 != nullptr) {
    float s = 0.f;
#pragma unroll 5
    for (int r = 0; r < RED_L1_BLKS; r++) s += partial2[r * 256 + t];
    red[t] = s;
  }
  __syncthreads();
  if (t < 128) {
    float a = 1.f, bm = 0.f;
    if (partial2 != nullptr) {
      float mu = red[t] * (1.f / NB);
      float var = red[128 + t] * (1.f / NB) - mu * mu;
      a = gamma[t] * rsqrtf(var + BN_EPS);
      bm = beta[t] - mu * a;
    }
    a_s[t] = a;
    b_s[t] = bm;
  }
  __syncthreads();
  if (t < 128) {
    float acc = bias_in ? bias_in[t] : 0.f;
    for (int k = 0; k < K; k++) acc += b_s[k] * W[k * 128 + t];
    bias_out[t] = acc;
  }
  int nkf = K >> 5;
  int total = nkf * 4096;  // 8 nf * nkf * 64 * 8
  for (int i = t; i < total; i += 256) {
    int j = i & 7;
    int lane = (i >> 3) & 63;
    int rem = i >> 9;          // nf*nkf + kf
    int kf = rem % nkf;
    int nf = rem / nkf;
    int k = kf * 32 + (lane >> 4) * 8 + j;
    int col = nf * 16 + (lane & 15);
    Bp[i] = f2b(a_s[k] * W[k * 128 + col]);
  }
}

// ---------------- bf16 MFMA GEMM: C[M,128] = A[M,K] @ Bp (+bias, opt relu) -
template <bool RELU>
__global__ __launch_bounds__(256) void gemm_mfma(const ushort* __restrict__ A,
                                                 const ushort* __restrict__ Bp,
                                                 const float* __restrict__ bias,
                                                 ushort* __restrict__ C, int M,
                                                 int K) {
  __shared__ ushort Blds[16384];
  const int tid = threadIdx.x;
  const int lane = tid & 63;
  const int w = tid >> 6;
  const int nkf = K >> 5;
  for (int i = tid; i < nkf * 512; i += 256)
    reinterpret_cast<uint4*>(Blds)[i] = reinterpret_cast<const uint4*>(Bp)[i];
  __syncthreads();

  const int rbase = blockIdx.x * 128 + w * 32;
  f32x4 acc[2][8];
#pragma unroll
  for (int m = 0; m < 2; m++)
#pragma unroll
    for (int n = 0; n < 8; n++) acc[m][n] = (f32x4){0.f, 0.f, 0.f, 0.f};

  const int arow0 = rbase + (lane & 15);
  const int acol = (lane >> 4) * 8;
#pragma unroll 4
  for (int kf = 0; kf < nkf; kf++) {
    bf16x8 a0 = *reinterpret_cast<const bf16x8*>(
        A + (size_t)arow0 * K + kf * 32 + acol);
    bf16x8 a1 = *reinterpret_cast<const bf16x8*>(
        A + (size_t)(arow0 + 16) * K + kf * 32 + acol);
#pragma unroll
    for (int nf = 0; nf < 8; nf++) {
      bf16x8 b = *reinterpret_cast<const bf16x8*>(
          &Blds[((nf * nkf + kf) * 64 + lane) * 8]);
      acc[0][nf] = __builtin_amdgcn_mfma_f32_16x16x32_bf16(a0, b, acc[0][nf], 0, 0, 0);
      acc[1][nf] = __builtin_amdgcn_mfma_f32_16x16x32_bf16(a1, b, acc[1][nf], 0, 0, 0);
    }
  }

#pragma unroll
  for (int m = 0; m < 2; m++) {
    int row0 = rbase + m * 16 + (lane >> 4) * 4;
#pragma unroll
    for (int nf = 0; nf < 8; nf++) {
      int col = nf * 16 + (lane & 15);
      float bv = bias[col];
#pragma unroll
      for (int r = 0; r < 4; r++) {
        int row = row0 + r;
        if (row < M) {
          float v = acc[m][nf][r] + bv;
          if (RELU) v = fmaxf(v, 0.f);
          C[(size_t)row * 128 + col] = f2b(v);
        }
      }
    }
  }
}

// ---------------- conv aggregation: CSR gather + fused stats partials -----
// y[v] = relu(bias + h[v]*dis[v]^2 + sum_e h[e_src]*e_w); per-block channel
// sums/sumsqs -> partial[bid][256] (no atomics).
__global__ __launch_bounds__(256) void gather_conv(
    const ushort* __restrict__ h, const int* __restrict__ e_src,
    const float* __restrict__ e_w, const int* __restrict__ row_ptr,
    const float* __restrict__ dis, const float* __restrict__ bias,
    ushort* __restrict__ y, float* __restrict__ partial) {
  __shared__ float red[2048];
  int tid = threadIdx.x;
  int gid = blockIdx.x * 256 + tid;
  int v = gid >> 4;           // grid == NB*16 exactly, all threads valid
  int c8 = gid & 15;
  const uint4* h4 = reinterpret_cast<const uint4*>(h);
  float s = dis[v];
  float ss = s * s;
  uint4 hv = h4[(size_t)v * 16 + c8];
  float acc[8];
  acc[0] = bias[c8 * 8 + 0] + blo(hv.x) * ss;
  acc[1] = bias[c8 * 8 + 1] + bhi(hv.x) * ss;
  acc[2] = bias[c8 * 8 + 2] + blo(hv.y) * ss;
  acc[3] = bias[c8 * 8 + 3] + bhi(hv.y) * ss;
  acc[4] = bias[c8 * 8 + 4] + blo(hv.z) * ss;
  acc[5] = bias[c8 * 8 + 5] + bhi(hv.z) * ss;
  acc[6] = bias[c8 * 8 + 6] + blo(hv.w) * ss;
  acc[7] = bias[c8 * 8 + 7] + bhi(hv.w) * ss;
  int beg = row_ptr[v], end = row_ptr[v + 1];
  for (int e = beg; e < end; ++e) {
    int si = e_src[e];
    float ew = e_w[e];
    uint4 q = h4[(size_t)si * 16 + c8];
    acc[0] += blo(q.x) * ew;
    acc[1] += bhi(q.x) * ew;
    acc[2] += blo(q.y) * ew;
    acc[3] += bhi(q.y) * ew;
    acc[4] += blo(q.z) * ew;
    acc[5] += bhi(q.z) * ew;
    acc[6] += blo(q.w) * ew;
    acc[7] += bhi(q.w) * ew;
  }
#pragma unroll
  for (int j = 0; j < 8; j++) acc[j] = fmaxf(acc[j], 0.f);
  uint4 o;
  o.x = (uint)f2b(acc[0]) | ((uint)f2b(acc[1]) << 16);
  o.y = (uint)f2b(acc[2]) | ((uint)f2b(acc[3]) << 16);
  o.z = (uint)f2b(acc[4]) | ((uint)f2b(acc[5]) << 16);
  o.w = (uint)f2b(acc[6]) | ((uint)f2b(acc[7]) << 16);
  reinterpret_cast<uint4*>(y)[(size_t)v * 16 + c8] = o;

  // --- fused per-block stats: sum then sumsq (tree over node dim) ---
#pragma unroll
  for (int j = 0; j < 8; j++) red[tid * 8 + j] = acc[j];
  __syncthreads();
  for (int st = 128; st >= 16; st >>= 1) {
    if (tid < st)
#pragma unroll
      for (int j = 0; j < 8; j++) red[tid * 8 + j] += red[(tid + st) * 8 + j];
    __syncthreads();
  }
  if (tid < 16)
#pragma unroll
    for (int j = 0; j < 8; j++)
      partial[(size_t)blockIdx.x * 256 + tid * 8 + j] = red[tid * 8 + j];
  __syncthreads();
#pragma unroll
  for (int j = 0; j < 8; j++) red[tid * 8 + j] = acc[j] * acc[j];
  __syncthreads();
  for (int st = 128; st >= 16; st >>= 1) {
    if (tid < st)
#pragma unroll
      for (int j = 0; j < 8; j++) red[tid * 8 + j] += red[(tid + st) * 8 + j];
    __syncthreads();
  }
  if (tid < 16)
#pragma unroll
    for (int j = 0; j < 8; j++)
      partial[(size_t)blockIdx.x * 256 + 128 + tid * 8 + j] = red[tid * 8 + j];
}

// ---------------- stats level-1 reduce: [3125][256] -> [125][256] ---------
__global__ __launch_bounds__(256) void reduce_l1(const float* __restrict__ partial,
                                                 float* __restrict__ partial2) {
  int tid = threadIdx.x;
  int b = blockIdx.x;
  float s = 0.f;
#pragma unroll 5
  for (int r = b * 25; r < b * 25 + 25; r++) s += partial[(size_t)r * 256 + tid];
  partial2[(size_t)b * 256 + tid] = s;
}

// ---------------- pooling ----------------
__global__ __launch_bounds__(256) void graph_bounds(const int* __restrict__ batch,
                                                    int* __restrict__ g_start) {
  int g = blockIdx.x * 256 + threadIdx.x;
  if (g > NG) return;
  if (g == NG) { g_start[NG] = NB; return; }
  int lo = 0, hi = NB;
  while (lo < hi) {
    int mid = (lo + hi) >> 1;
    if (batch[mid] < g) lo = mid + 1; else hi = mid;
  }
  g_start[g] = lo;
}

__global__ __launch_bounds__(256) void pool_gather(const ushort* __restrict__ emb,
                                                   const int* __restrict__ g_start,
                                                   float* __restrict__ g) {
  int gid = blockIdx.x * 256 + threadIdx.x;
  int gr = gid >> 4;
  if (gr >= NG) return;
  int c8 = gid & 15;
  const uint4* e4 = reinterpret_cast<const uint4*>(emb);
  float acc[8];
#pragma unroll
  for (int j = 0; j < 8; j++) acc[j] = 0.f;
  int beg = g_start[gr], end = g_start[gr + 1];
  for (int v = beg; v < end; ++v) {
    uint4 q = e4[(size_t)v * 16 + c8];
    acc[0] += blo(q.x); acc[1] += bhi(q.x);
    acc[2] += blo(q.y); acc[3] += bhi(q.y);
    acc[4] += blo(q.z); acc[5] += bhi(q.z);
    acc[6] += blo(q.w); acc[7] += bhi(q.w);
  }
  float4* gp = reinterpret_cast<float4*>(g + (size_t)gr * 128 + c8 * 8);
  gp[0] = make_float4(acc[0], acc[1], acc[2], acc[3]);
  gp[1] = make_float4(acc[4], acc[5], acc[6], acc[7]);
}

// ---------------- head: 8 graphs per block, weights in LDS ----------------
__global__ __launch_bounds__(128) void head_kernel(
    const float* __restrict__ g, const float* __restrict__ w1,
    const float* __restrict__ b1, const float* __restrict__ w2,
    const float* __restrict__ b2, const float* __restrict__ wp,
    const float* __restrict__ bp, float* __restrict__ out) {
  __shared__ float w1s[128 * 64];
  __shared__ float w2s[64 * 32];
  __shared__ float wps[64];
  __shared__ float sg[128], ph[128], sh1[64], sh2[32];
  int tid = threadIdx.x;
  for (int i = tid; i < 2048; i += 128)
    reinterpret_cast<float4*>(w1s)[i] = reinterpret_cast<const float4*>(w1)[i];
  for (int i = tid; i < 512; i += 128)
    reinterpret_cast<float4*>(w2s)[i] = reinterpret_cast<const float4*>(w2)[i];
  if (tid < 64) wps[tid] = wp[tid];
  __syncthreads();

  for (int gi = 0; gi < 8; gi++) {
    int gid = blockIdx.x * 8 + gi;
    if (gid >= NG) break;
    sg[tid] = g[(size_t)gid * 128 + tid];
    __syncthreads();
    {
      int o = tid & 63, h = tid >> 6;
      float acc = 0.f;
#pragma unroll 8
      for (int k = 0; k < 64; k++) acc += sg[h * 64 + k] * w1s[(h * 64 + k) * 64 + o];
      ph[tid] = acc;
    }
    __syncthreads();
    if (tid < 64) sh1[tid] = fmaxf(b1[tid] + ph[tid] + ph[tid + 64], 0.f);
    __syncthreads();
    {
      int o = tid & 31, q = tid >> 5;
      float acc = 0.f;
#pragma unroll 8
      for (int k = 0; k < 16; k++) acc += sh1[q * 16 + k] * w2s[(q * 16 + k) * 32 + o];
      ph[tid] = acc;
    }
    __syncthreads();
    if (tid < 32)
      sh2[tid] = fmaxf(b2[tid] + ph[tid] + ph[tid + 32] + ph[tid + 64] + ph[tid + 96], 0.f);
    __syncthreads();
    if (tid < 2) {
      float acc = bp[tid];
#pragma unroll
      for (int k = 0; k < 32; k++) acc += sh2[k] * wp[k * 2 + tid];
      out[(size_t)gid * 2 + tid] = acc;
    }
    __syncthreads();
  }
}

extern "C" void kernel_launch(void* const* d_in, const int* in_sizes, int n_in,
                              void* d_out, int out_size, void* d_ws,
                              size_t ws_size, hipStream_t stream) {
  const float* x = (const float*)d_in[0];
  const int* ei = (const int*)d_in[1];
  const int* batch = (const int*)d_in[2];
  const float* lin_w = (const float*)d_in[3];
  const float* lin_b = (const float*)d_in[4];
  const float* conv_w = (const float*)d_in[5];
  const float* conv_b = (const float*)d_in[6];
  const float* bn_g = (const float*)d_in[7];
  const float* bn_b = (const float*)d_in[8];
  const float* emb_w = (const float*)d_in[9];
  const float* emb_b = (const float*)d_in[10];
  const float* m1w = (const float*)d_in[11];
  const float* m1b = (const float*)d_in[12];
  const float* m2w = (const float*)d_in[13];
  const float* m2b = (const float*)d_in[14];
  const float* pw = (const float*)d_in[15];
  const float* pb = (const float*)d_in[16];
  float* out = (float*)d_out;

  ushort* buf0 = (ushort*)d_ws;                  // [MPAD,128] bf16
  ushort* buf1 = buf0 + (size_t)MPAD * 128;      // [MPAD,128] bf16
  ushort* xb = buf1 + (size_t)MPAD * 128;        // [MPAD,64] bf16
  ushort* Bp = xb + (size_t)MPAD * 64;           // 5 * 16384 packed weights
  float* fbase = (float*)(Bp + 5 * 16384);
  float* dis = fbase;                            // [NB] pad 50048
  float* partial = dis + 50048;                  // [3125*256]
  float* partial2 = partial + GATHER_BLKS * 256; // [125*256]
  float* biasb = partial2 + RED_L1_BLKS * 256;   // [5*128]
  float* e_w = biasb + 640;                      // [NE]
  float* g = e_w + NE;                           // [NG*128]
  int* cnt = (int*)(g + (size_t)NG * 128);       // [NB]
  int* row_ptr = cnt + NB;                       // [NB+1] pad 50008
  int* cursor = row_ptr + 50008;                 // [NB]
  int* e_src = cursor + NB;                      // [NE]
  int* bsum = e_src + NE;                        // [256]
  int* boffs = bsum + 256;                       // [256]
  int* g_start = boffs + 256;                    // [NG+1]

  const int* src = ei;
  const int* dst = ei + NE;

  hipMemsetAsync(cnt, 0, NB * sizeof(int), stream);
  hipMemsetAsync(cursor, 0, NB * sizeof(int), stream);

  deg_kernel<<<(NE + 255) / 256, 256, 0, stream>>>(dst, cnt);
  dis_kernel<<<NBLK, 256, 0, stream>>>(cnt, dis);
  scan1<<<NBLK, 256, 0, stream>>>(cnt, row_ptr, bsum);
  scan2<<<1, 256, 0, stream>>>(bsum, boffs);
  scan3<<<NBLK, 256, 0, stream>>>(row_ptr, boffs);
  fill_csr<<<(NE + 255) / 256, 256, 0, stream>>>(src, dst, dis, row_ptr, cursor,
                                                 e_src, e_w);
  graph_bounds<<<(NG + 256) / 256, 256, 0, stream>>>(batch, g_start);

  cvt_x<<<(NB * ND / 4 + 255) / 256, 256, 0, stream>>>(x, xb);

  ushort* Bp0 = Bp;                // lin (K=64)
  ushort* Bp1 = Bp + 16384;        // conv0
  ushort* Bp2 = Bp + 2 * 16384;    // conv1 (BN0 folded)
  ushort* Bp3 = Bp + 3 * 16384;    // conv2 (BN1 folded)
  ushort* Bp4 = Bp + 4 * 16384;    // emb  (BN2 folded)
  float* bias0 = biasb;
  float* bias1 = biasb + 128;
  float* bias2 = biasb + 256;
  float* bias3 = biasb + 384;
  float* bias4 = biasb + 512;

  prep_w<<<1, 256, 0, stream>>>(lin_w, 64, nullptr, nullptr, nullptr, lin_b,
                                Bp0, bias0);
  prep_w<<<1, 256, 0, stream>>>(conv_w, 128, nullptr, nullptr, nullptr,
                                nullptr, Bp1, bias1);

  const int GB = (NB + 127) / 128;

  // linatoms
  gemm_mfma<false><<<GB, 256, 0, stream>>>(xb, Bp0, bias0, buf0, NB, 64);

  // layer 0
  gemm_mfma<false><<<GB, 256, 0, stream>>>(buf0, Bp1, bias1, buf1, NB, 128);
  gather_conv<<<GATHER_BLKS, 256, 0, stream>>>(buf1, e_src, e_w, row_ptr, dis,
                                               conv_b, buf0, partial);
  reduce_l1<<<RED_L1_BLKS, 256, 0, stream>>>(partial, partial2);
  prep_w<<<1, 256, 0, stream>>>(conv_w + 16384, 128, partial2, bn_g, bn_b,
                                nullptr, Bp2, bias2);
  // layer 1
  gemm_mfma<false><<<GB, 256, 0, stream>>>(buf0, Bp2, bias2, buf1, NB, 128);
  gather_conv<<<GATHER_BLKS, 256, 0, stream>>>(buf1, e_src, e_w, row_ptr, dis,
                                               conv_b + 128, buf0, partial);
  reduce_l1<<<RED_L1_BLKS, 256, 0, stream>>>(partial, partial2);
  prep_w<<<1, 256, 0, stream>>>(conv_w + 2 * 16384, 128, partial2, bn_g + 128,
                                bn_b + 128, nullptr, Bp3, bias3);
  // layer 2
  gemm_mfma<false><<<GB, 256, 0, stream>>>(buf0, Bp3, bias3, buf1, NB, 128);
  gather_conv<<<GATHER_BLKS, 256, 0, stream>>>(buf1, e_src, e_w, row_ptr, dis,
                                               conv_b + 256, buf0, partial);
  reduce_l1<<<RED_L1_BLKS, 256, 0, stream>>>(partial, partial2);
  prep_w<<<1, 256, 0, stream>>>(emb_w, 128, partial2, bn_g + 256, bn_b + 256,
                                emb_b, Bp4, bias4);
  // emb + pool + head
  gemm_mfma<true><<<GB, 256, 0, stream>>>(buf0, Bp4, bias4, buf1, NB, 128);
  pool_gather<<<(NG * 16 + 255) / 256, 256, 0, stream>>>(buf1, g_start, g);
  head_kernel<<<(NG + 7) / 8, 128, 0, stream>>>(g, m1w, m1b, m2w, m2b, pw, pb,
                                                out);
}

// Round 5
// 378.370 us; speedup vs baseline: 1.4266x; 1.0592x over previous
//
#include <hip/hip_runtime.h>
#include <math.h>

#define NB 50000
#define NE 600000
#define NG 2000
#define ND 64
#define HID 128
#define BN_EPS 1e-5f
#define NBLK 196        // ceil(NB/256)
#define MPAD 50176      // 392*128, padded rows for GEMM tiles
#define GATHER_BLKS 3125  // NB*16/256 exactly
#define RED_L1_BLKS 125   // 3125/25

typedef __attribute__((ext_vector_type(8))) short bf16x8;
typedef __attribute__((ext_vector_type(4))) float f32x4;
typedef unsigned int uint;
typedef unsigned short ushort;

__device__ __forceinline__ ushort f2b(float f) {
  uint u = __builtin_bit_cast(uint, f);
  u = u + 0x7fffu + ((u >> 16) & 1u);   // RNE
  return (ushort)(u >> 16);
}
__device__ __forceinline__ float blo(uint u) {
  return __builtin_bit_cast(float, u << 16);
}
__device__ __forceinline__ float bhi(uint u) {
  return __builtin_bit_cast(float, u & 0xffff0000u);
}

// ---------------- degree / normalization ----------------
__global__ __launch_bounds__(256) void deg_kernel(const int* __restrict__ dst,
                                                  int* __restrict__ cnt) {
  int e = blockIdx.x * 256 + threadIdx.x;
  if (e < NE) atomicAdd(&cnt[dst[e]], 1);
}

__global__ __launch_bounds__(256) void dis_kernel(const int* __restrict__ cnt,
                                                  float* __restrict__ dis) {
  int v = blockIdx.x * 256 + threadIdx.x;
  if (v < NB) dis[v] = rsqrtf((float)(cnt[v] + 1));  // +1 self-loop
}

// ---------------- prefix scan ----------------
__global__ __launch_bounds__(256) void scan1(const int* __restrict__ cnt,
                                             int* __restrict__ part,
                                             int* __restrict__ bsum) {
  __shared__ int tmp[256];
  int tid = threadIdx.x;
  int i = blockIdx.x * 256 + tid;
  int v = (i < NB) ? cnt[i] : 0;
  tmp[tid] = v;
  __syncthreads();
  for (int off = 1; off < 256; off <<= 1) {
    int t = (tid >= off) ? tmp[tid - off] : 0;
    __syncthreads();
    tmp[tid] += t;
    __syncthreads();
  }
  if (i < NB) part[i] = tmp[tid] - v;
  if (tid == 255) bsum[blockIdx.x] = tmp[255];
}

__global__ __launch_bounds__(256) void scan2(int* __restrict__ bsum,
                                             int* __restrict__ boffs) {
  __shared__ int tmp[256];
  int tid = threadIdx.x;
  int v = (tid < NBLK) ? bsum[tid] : 0;
  tmp[tid] = v;
  __syncthreads();
  for (int off = 1; off < 256; off <<= 1) {
    int t = (tid >= off) ? tmp[tid - off] : 0;
    __syncthreads();
    tmp[tid] += t;
    __syncthreads();
  }
  if (tid < NBLK) boffs[tid] = tmp[tid] - v;
}

// writes row_ptr AND the atomic cursor copy
__global__ __launch_bounds__(256) void scan3(int* __restrict__ part,
                                             const int* __restrict__ boffs,
                                             int* __restrict__ cursor) {
  int i = blockIdx.x * 256 + threadIdx.x;
  if (i < NB) {
    int v = part[i] + boffs[blockIdx.x];
    part[i] = v;
    cursor[i] = v;
  }
  if (i == 0) part[NB] = NE;
}

// ---------------- CSR fill: one 8B packed write per edge ------------------
__global__ __launch_bounds__(256) void fill_csr(const int* __restrict__ src,
                                                const int* __restrict__ dst,
                                                const float* __restrict__ dis,
                                                int* __restrict__ cursor,
                                                int2* __restrict__ edata) {
  int e = blockIdx.x * 256 + threadIdx.x;
  if (e >= NE) return;
  int s = src[e], d = dst[e];
  int pos = atomicAdd(&cursor[d], 1);
  edata[pos] = make_int2(s, __builtin_bit_cast(int, dis[s] * dis[d]));
}

// ---------------- input f32 -> bf16 ----------------
__global__ __launch_bounds__(256) void cvt_x(const float* __restrict__ x,
                                             ushort* __restrict__ xb) {
  int i = blockIdx.x * 256 + threadIdx.x;
  if (i >= NB * ND / 4) return;
  float4 v = reinterpret_cast<const float4*>(x)[i];
  ushort4 o;
  o.x = f2b(v.x); o.y = f2b(v.y); o.z = f2b(v.z); o.w = f2b(v.w);
  reinterpret_cast<ushort4*>(xb)[i] = o;
}

// ---------------- stats finalize + BN fold coefficients -------------------
// partial2: [125][256] (sum[128], sumsq[128]) or nullptr (a=1, bm=0).
// ab[t] = a (BN scale folded into next W); bias_out = bias_in + bm @ W.
__global__ __launch_bounds__(256) void finalize_stats(
    const float* __restrict__ partial2, const float* __restrict__ gamma,
    const float* __restrict__ beta, const float* __restrict__ W, int K,
    const float* __restrict__ bias_in, float* __restrict__ ab,
    float* __restrict__ bias_out) {
  __shared__ float red[256], b_s[128];
  int t = threadIdx.x;
  float a = 1.f, bm = 0.f;
  if (partial2 != nullptr) {
    float s = 0.f;
#pragma unroll 5
    for (int r = 0; r < RED_L1_BLKS; r++) s += partial2[r * 256 + t];
    red[t] = s;
    __syncthreads();
    if (t < 128) {
      float mu = red[t] * (1.f / NB);
      float var = red[128 + t] * (1.f / NB) - mu * mu;
      a = gamma[t] * rsqrtf(var + BN_EPS);
      bm = beta[t] - mu * a;
    }
  }
  if (t < 128) { ab[t] = a; b_s[t] = bm; }
  __syncthreads();
  if (t < 128) {
    float acc = bias_in ? bias_in[t] : 0.f;
    if (partial2 != nullptr) {
      for (int k = 0; k < K; k++) acc += b_s[k] * W[k * 128 + t];
    }
    bias_out[t] = acc;
  }
}

// ---------------- weight packing (parallel): W*a -> MFMA fragment order ---
// Bp[((nf*nkf+kf)*64+lane)*8+j] = a[k] * W[k][nf*16+(lane&15)],
// k = kf*32+(lane>>4)*8+j
__global__ __launch_bounds__(256) void pack_w(const float* __restrict__ W,
                                              int K,
                                              const float* __restrict__ ab,
                                              ushort* __restrict__ Bp) {
  int nkf = K >> 5;
  int total = nkf * 4096;
  for (int i = blockIdx.x * 256 + threadIdx.x; i < total; i += gridDim.x * 256) {
    int j = i & 7;
    int lane = (i >> 3) & 63;
    int rem = i >> 9;
    int kf = rem % nkf;
    int nf = rem / nkf;
    int k = kf * 32 + (lane >> 4) * 8 + j;
    int col = nf * 16 + (lane & 15);
    Bp[i] = f2b(ab[k] * W[k * 128 + col]);
  }
}

// ---------------- bf16 MFMA GEMM: C[M,128] = A[M,K] @ Bp (+bias, opt relu) -
template <bool RELU>
__global__ __launch_bounds__(256) void gemm_mfma(const ushort* __restrict__ A,
                                                 const ushort* __restrict__ Bp,
                                                 const float* __restrict__ bias,
                                                 ushort* __restrict__ C, int M,
                                                 int K) {
  __shared__ ushort Blds[16384];
  const int tid = threadIdx.x;
  const int lane = tid & 63;
  const int w = tid >> 6;
  const int nkf = K >> 5;
  for (int i = tid; i < nkf * 512; i += 256)
    reinterpret_cast<uint4*>(Blds)[i] = reinterpret_cast<const uint4*>(Bp)[i];
  __syncthreads();

  const int rbase = blockIdx.x * 128 + w * 32;
  f32x4 acc[2][8];
#pragma unroll
  for (int m = 0; m < 2; m++)
#pragma unroll
    for (int n = 0; n < 8; n++) acc[m][n] = (f32x4){0.f, 0.f, 0.f, 0.f};

  const int arow0 = rbase + (lane & 15);
  const int acol = (lane >> 4) * 8;
#pragma unroll 4
  for (int kf = 0; kf < nkf; kf++) {
    bf16x8 a0 = *reinterpret_cast<const bf16x8*>(
        A + (size_t)arow0 * K + kf * 32 + acol);
    bf16x8 a1 = *reinterpret_cast<const bf16x8*>(
        A + (size_t)(arow0 + 16) * K + kf * 32 + acol);
#pragma unroll
    for (int nf = 0; nf < 8; nf++) {
      bf16x8 b = *reinterpret_cast<const bf16x8*>(
          &Blds[((nf * nkf + kf) * 64 + lane) * 8]);
      acc[0][nf] = __builtin_amdgcn_mfma_f32_16x16x32_bf16(a0, b, acc[0][nf], 0, 0, 0);
      acc[1][nf] = __builtin_amdgcn_mfma_f32_16x16x32_bf16(a1, b, acc[1][nf], 0, 0, 0);
    }
  }

#pragma unroll
  for (int m = 0; m < 2; m++) {
    int row0 = rbase + m * 16 + (lane >> 4) * 4;
#pragma unroll
    for (int nf = 0; nf < 8; nf++) {
      int col = nf * 16 + (lane & 15);
      float bv = bias[col];
#pragma unroll
      for (int r = 0; r < 4; r++) {
        int row = row0 + r;
        if (row < M) {
          float v = acc[m][nf][r] + bv;
          if (RELU) v = fmaxf(v, 0.f);
          C[(size_t)row * 128 + col] = f2b(v);
        }
      }
    }
  }
}

// ---------------- conv aggregation: CSR gather + fused stats partials -----
__global__ __launch_bounds__(256) void gather_conv(
    const ushort* __restrict__ h, const int2* __restrict__ edata,
    const int* __restrict__ row_ptr, const float* __restrict__ dis,
    const float* __restrict__ bias, ushort* __restrict__ y,
    float* __restrict__ partial) {
  __shared__ float red[2048];
  int tid = threadIdx.x;
  int gid = blockIdx.x * 256 + tid;
  int v = gid >> 4;           // grid == NB*16 exactly
  int c8 = gid & 15;
  const uint4* h4 = reinterpret_cast<const uint4*>(h);
  float s = dis[v];
  float ss = s * s;
  uint4 hv = h4[(size_t)v * 16 + c8];
  float acc[8];
  acc[0] = bias[c8 * 8 + 0] + blo(hv.x) * ss;
  acc[1] = bias[c8 * 8 + 1] + bhi(hv.x) * ss;
  acc[2] = bias[c8 * 8 + 2] + blo(hv.y) * ss;
  acc[3] = bias[c8 * 8 + 3] + bhi(hv.y) * ss;
  acc[4] = bias[c8 * 8 + 4] + blo(hv.z) * ss;
  acc[5] = bias[c8 * 8 + 5] + bhi(hv.z) * ss;
  acc[6] = bias[c8 * 8 + 6] + blo(hv.w) * ss;
  acc[7] = bias[c8 * 8 + 7] + bhi(hv.w) * ss;
  int beg = row_ptr[v], end = row_ptr[v + 1];
  for (int e = beg; e < end; ++e) {
    int2 ed = edata[e];
    float ew = __builtin_bit_cast(float, ed.y);
    uint4 q = h4[(size_t)ed.x * 16 + c8];
    acc[0] += blo(q.x) * ew;
    acc[1] += bhi(q.x) * ew;
    acc[2] += blo(q.y) * ew;
    acc[3] += bhi(q.y) * ew;
    acc[4] += blo(q.z) * ew;
    acc[5] += bhi(q.z) * ew;
    acc[6] += blo(q.w) * ew;
    acc[7] += bhi(q.w) * ew;
  }
#pragma unroll
  for (int j = 0; j < 8; j++) acc[j] = fmaxf(acc[j], 0.f);
  uint4 o;
  o.x = (uint)f2b(acc[0]) | ((uint)f2b(acc[1]) << 16);
  o.y = (uint)f2b(acc[2]) | ((uint)f2b(acc[3]) << 16);
  o.z = (uint)f2b(acc[4]) | ((uint)f2b(acc[5]) << 16);
  o.w = (uint)f2b(acc[6]) | ((uint)f2b(acc[7]) << 16);
  reinterpret_cast<uint4*>(y)[(size_t)v * 16 + c8] = o;

  // fused per-block stats partials (no atomics)
#pragma unroll
  for (int j = 0; j < 8; j++) red[tid * 8 + j] = acc[j];
  __syncthreads();
  for (int st = 128; st >= 16; st >>= 1) {
    if (tid < st)
#pragma unroll
      for (int j = 0; j < 8; j++) red[tid * 8 + j] += red[(tid + st) * 8 + j];
    __syncthreads();
  }
  if (tid < 16)
#pragma unroll
    for (int j = 0; j < 8; j++)
      partial[(size_t)blockIdx.x * 256 + tid * 8 + j] = red[tid * 8 + j];
  __syncthreads();
#pragma unroll
  for (int j = 0; j < 8; j++) red[tid * 8 + j] = acc[j] * acc[j];
  __syncthreads();
  for (int st = 128; st >= 16; st >>= 1) {
    if (tid < st)
#pragma unroll
      for (int j = 0; j < 8; j++) red[tid * 8 + j] += red[(tid + st) * 8 + j];
    __syncthreads();
  }
  if (tid < 16)
#pragma unroll
    for (int j = 0; j < 8; j++)
      partial[(size_t)blockIdx.x * 256 + 128 + tid * 8 + j] = red[tid * 8 + j];
}

// ---------------- stats level-1 reduce: [3125][256] -> [125][256] ---------
__global__ __launch_bounds__(256) void reduce_l1(const float* __restrict__ partial,
                                                 float* __restrict__ partial2) {
  int tid = threadIdx.x;
  int b = blockIdx.x;
  float s = 0.f;
#pragma unroll 5
  for (int r = b * 25; r < b * 25 + 25; r++) s += partial[(size_t)r * 256 + tid];
  partial2[(size_t)b * 256 + tid] = s;
}

// ---------------- pooling ----------------
__global__ __launch_bounds__(256) void graph_bounds(const int* __restrict__ batch,
                                                    int* __restrict__ g_start) {
  int g = blockIdx.x * 256 + threadIdx.x;
  if (g > NG) return;
  if (g == NG) { g_start[NG] = NB; return; }
  int lo = 0, hi = NB;
  while (lo < hi) {
    int mid = (lo + hi) >> 1;
    if (batch[mid] < g) lo = mid + 1; else hi = mid;
  }
  g_start[g] = lo;
}

__global__ __launch_bounds__(256) void pool_gather(const ushort* __restrict__ emb,
                                                   const int* __restrict__ g_start,
                                                   float* __restrict__ g) {
  int gid = blockIdx.x * 256 + threadIdx.x;
  int gr = gid >> 4;
  if (gr >= NG) return;
  int c8 = gid & 15;
  const uint4* e4 = reinterpret_cast<const uint4*>(emb);
  float acc[8];
#pragma unroll
  for (int j = 0; j < 8; j++) acc[j] = 0.f;
  int beg = g_start[gr], end = g_start[gr + 1];
  for (int v = beg; v < end; ++v) {
    uint4 q = e4[(size_t)v * 16 + c8];
    acc[0] += blo(q.x); acc[1] += bhi(q.x);
    acc[2] += blo(q.y); acc[3] += bhi(q.y);
    acc[4] += blo(q.z); acc[5] += bhi(q.z);
    acc[6] += blo(q.w); acc[7] += bhi(q.w);
  }
  float4* gp = reinterpret_cast<float4*>(g + (size_t)gr * 128 + c8 * 8);
  gp[0] = make_float4(acc[0], acc[1], acc[2], acc[3]);
  gp[1] = make_float4(acc[4], acc[5], acc[6], acc[7]);
}

// ---------------- head: 8 graphs per block, weights in LDS ----------------
__global__ __launch_bounds__(128) void head_kernel(
    const float* __restrict__ g, const float* __restrict__ w1,
    const float* __restrict__ b1, const float* __restrict__ w2,
    const float* __restrict__ b2, const float* __restrict__ wp,
    const float* __restrict__ bp, float* __restrict__ out) {
  __shared__ float w1s[128 * 64];
  __shared__ float w2s[64 * 32];
  __shared__ float wps[64];
  __shared__ float sg[128], ph[128], sh1[64], sh2[32];
  int tid = threadIdx.x;
  for (int i = tid; i < 2048; i += 128)
    reinterpret_cast<float4*>(w1s)[i] = reinterpret_cast<const float4*>(w1)[i];
  for (int i = tid; i < 512; i += 128)
    reinterpret_cast<float4*>(w2s)[i] = reinterpret_cast<const float4*>(w2)[i];
  if (tid < 64) wps[tid] = wp[tid];
  __syncthreads();

  for (int gi = 0; gi < 8; gi++) {
    int gid = blockIdx.x * 8 + gi;
    if (gid >= NG) break;
    sg[tid] = g[(size_t)gid * 128 + tid];
    __syncthreads();
    {
      int o = tid & 63, h = tid >> 6;
      float acc = 0.f;
#pragma unroll 8
      for (int k = 0; k < 64; k++) acc += sg[h * 64 + k] * w1s[(h * 64 + k) * 64 + o];
      ph[tid] = acc;
    }
    __syncthreads();
    if (tid < 64) sh1[tid] = fmaxf(b1[tid] + ph[tid] + ph[tid + 64], 0.f);
    __syncthreads();
    {
      int o = tid & 31, q = tid >> 5;
      float acc = 0.f;
#pragma unroll 8
      for (int k = 0; k < 16; k++) acc += sh1[q * 16 + k] * w2s[(q * 16 + k) * 32 + o];
      ph[tid] = acc;
    }
    __syncthreads();
    if (tid < 32)
      sh2[tid] = fmaxf(b2[tid] + ph[tid] + ph[tid + 32] + ph[tid + 64] + ph[tid + 96], 0.f);
    __syncthreads();
    if (tid < 2) {
      float acc = bp[tid];
#pragma unroll
      for (int k = 0; k < 32; k++) acc += sh2[k] * wps[k * 2 + tid];
      out[(size_t)gid * 2 + tid] = acc;
    }
    __syncthreads();
  }
}

extern "C" void kernel_launch(void* const* d_in, const int* in_sizes, int n_in,
                              void* d_out, int out_size, void* d_ws,
                              size_t ws_size, hipStream_t stream) {
  const float* x = (const float*)d_in[0];
  const int* ei = (const int*)d_in[1];
  const int* batch = (const int*)d_in[2];
  const float* lin_w = (const float*)d_in[3];
  const float* lin_b = (const float*)d_in[4];
  const float* conv_w = (const float*)d_in[5];
  const float* conv_b = (const float*)d_in[6];
  const float* bn_g = (const float*)d_in[7];
  const float* bn_b = (const float*)d_in[8];
  const float* emb_w = (const float*)d_in[9];
  const float* emb_b = (const float*)d_in[10];
  const float* m1w = (const float*)d_in[11];
  const float* m1b = (const float*)d_in[12];
  const float* m2w = (const float*)d_in[13];
  const float* m2b = (const float*)d_in[14];
  const float* pw = (const float*)d_in[15];
  const float* pb = (const float*)d_in[16];
  float* out = (float*)d_out;

  ushort* buf0 = (ushort*)d_ws;                  // [MPAD,128] bf16
  ushort* buf1 = buf0 + (size_t)MPAD * 128;      // [MPAD,128] bf16
  ushort* xb = buf1 + (size_t)MPAD * 128;        // [MPAD,64] bf16
  ushort* Bp = xb + (size_t)MPAD * 64;           // 5 * 16384 packed weights
  int2* edata = (int2*)(Bp + 5 * 16384);         // [NE] packed (src, w) — 8B aligned
  float* fbase = (float*)(edata + NE);
  float* dis = fbase;                            // [NB] pad 50048
  float* partial = dis + 50048;                  // [3125*256]
  float* partial2 = partial + GATHER_BLKS * 256; // [125*256]
  float* biasb = partial2 + RED_L1_BLKS * 256;   // [5*128]
  float* ab = biasb + 640;                       // [128]
  float* g = ab + 128;                           // [NG*128]
  int* cnt = (int*)(g + (size_t)NG * 128);       // [NB]
  int* row_ptr = cnt + NB;                       // [NB+1] pad 50008
  int* cursor = row_ptr + 50008;                 // [NB]
  int* bsum = cursor + NB;                       // [256]
  int* boffs = bsum + 256;                       // [256]
  int* g_start = boffs + 256;                    // [NG+1]

  const int* src = ei;
  const int* dst = ei + NE;

  hipMemsetAsync(cnt, 0, NB * sizeof(int), stream);

  deg_kernel<<<(NE + 255) / 256, 256, 0, stream>>>(dst, cnt);
  dis_kernel<<<NBLK, 256, 0, stream>>>(cnt, dis);
  scan1<<<NBLK, 256, 0, stream>>>(cnt, row_ptr, bsum);
  scan2<<<1, 256, 0, stream>>>(bsum, boffs);
  scan3<<<NBLK, 256, 0, stream>>>(row_ptr, boffs, cursor);
  fill_csr<<<(NE + 255) / 256, 256, 0, stream>>>(src, dst, dis, cursor, edata);
  graph_bounds<<<(NG + 256) / 256, 256, 0, stream>>>(batch, g_start);

  cvt_x<<<(NB * ND / 4 + 255) / 256, 256, 0, stream>>>(x, xb);

  ushort* Bp0 = Bp;                // lin (K=64)
  ushort* Bp1 = Bp + 16384;        // conv0
  ushort* Bp2 = Bp + 2 * 16384;    // conv1 (BN0 folded)
  ushort* Bp3 = Bp + 3 * 16384;    // conv2 (BN1 folded)
  ushort* Bp4 = Bp + 4 * 16384;    // emb  (BN2 folded)
  float* bias0 = biasb;
  float* bias1 = biasb + 128;
  float* bias2 = biasb + 256;
  float* bias3 = biasb + 384;
  float* bias4 = biasb + 512;

  finalize_stats<<<1, 256, 0, stream>>>(nullptr, nullptr, nullptr, nullptr, 64,
                                        lin_b, ab, bias0);
  pack_w<<<8, 256, 0, stream>>>(lin_w, 64, ab, Bp0);
  finalize_stats<<<1, 256, 0, stream>>>(nullptr, nullptr, nullptr, nullptr, 128,
                                        nullptr, ab, bias1);
  pack_w<<<16, 256, 0, stream>>>(conv_w, 128, ab, Bp1);

  const int GB = (NB + 127) / 128;

  // linatoms
  gemm_mfma<false><<<GB, 256, 0, stream>>>(xb, Bp0, bias0, buf0, NB, 64);

  // layer 0
  gemm_mfma<false><<<GB, 256, 0, stream>>>(buf0, Bp1, bias1, buf1, NB, 128);
  gather_conv<<<GATHER_BLKS, 256, 0, stream>>>(buf1, edata, row_ptr, dis,
                                               conv_b, buf0, partial);
  reduce_l1<<<RED_L1_BLKS, 256, 0, stream>>>(partial, partial2);
  finalize_stats<<<1, 256, 0, stream>>>(partial2, bn_g, bn_b, conv_w + 16384,
                                        128, nullptr, ab, bias2);
  pack_w<<<16, 256, 0, stream>>>(conv_w + 16384, 128, ab, Bp2);
  // layer 1
  gemm_mfma<false><<<GB, 256, 0, stream>>>(buf0, Bp2, bias2, buf1, NB, 128);
  gather_conv<<<GATHER_BLKS, 256, 0, stream>>>(buf1, edata, row_ptr, dis,
                                               conv_b + 128, buf0, partial);
  reduce_l1<<<RED_L1_BLKS, 256, 0, stream>>>(partial, partial2);
  finalize_stats<<<1, 256, 0, stream>>>(partial2, bn_g + 128, bn_b + 128,
                                        conv_w + 2 * 16384, 128, nullptr, ab,
                                        bias3);
  pack_w<<<16, 256, 0, stream>>>(conv_w + 2 * 16384, 128, ab, Bp3);
  // layer 2
  gemm_mfma<false><<<GB, 256, 0, stream>>>(buf0, Bp3, bias3, buf1, NB, 128);
  gather_conv<<<GATHER_BLKS, 256, 0, stream>>>(buf1, edata, row_ptr, dis,
                                               conv_b + 256, buf0, partial);
  reduce_l1<<<RED_L1_BLKS, 256, 0, stream>>>(partial, partial2);
  finalize_stats<<<1, 256, 0, stream>>>(partial2, bn_g + 256, bn_b + 256, emb_w,
                                        128, emb_b, ab, bias4);
  pack_w<<<16, 256, 0, stream>>>(emb_w, 128, ab, Bp4);
  // emb + pool + head
  gemm_mfma<true><<<GB, 256, 0, stream>>>(buf0, Bp4, bias4, buf1, NB, 128);
  pool_gather<<<(NG * 16 + 255) / 256, 256, 0, stream>>>(buf1, g_start, g);
  head_kernel<<<(NG + 7) / 8, 128, 0, stream>>>(g, m1w, m1b, m2w, m2b, pw, pb,
                                                out);
}